// Round 17
// baseline (84.810 us; speedup 1.0000x reference)
//
#include <hip/hip_runtime.h>
#include <hip/hip_bf16.h>
#include <math.h>

#define S_ 64
#define B_ 128
#define H_ 768
#define A_ 768

typedef __bf16 bf16_t;
typedef __attribute__((ext_vector_type(8))) __bf16 bf16x8;
typedef __attribute__((ext_vector_type(4))) __bf16 bf16x4;
typedef __attribute__((ext_vector_type(2))) __bf16 bf16x2;
typedef __attribute__((ext_vector_type(4))) float f32x4;

__device__ __forceinline__ bf16x8 pack8(f32x4 a, f32x4 b) {
    bf16x8 o;
    o[0]=(bf16_t)a[0]; o[1]=(bf16_t)a[1]; o[2]=(bf16_t)a[2]; o[3]=(bf16_t)a[3];
    o[4]=(bf16_t)b[0]; o[5]=(bf16_t)b[1]; o[6]=(bf16_t)b[2]; o[7]=(bf16_t)b[3];
    return o;
}

// ============================================================================
// FAST PATH: single fused GEMM (reads raw f32 inputs; no prep passes) + attn
// ============================================================================

// BM=128 x BN=192, BK=64, 512 thr (8 waves, 2M x 4N), 24 MFMA/wave/K-step.
// r15 base (write-early/load-late, lgkm-only barriers, tn-major tile order,
// (512,2)). ONE change: W staging uses TWO register sets (wreg0/wreg1) so
// each W load gets a 2-ITERATION latency window before its ds_write
// consumes it (A keeps the proven 1-iter window). Parity is compile-time
// (full unroll), sets are separate named captures -> no dynamic indexing.
__global__ __launch_bounds__(512, 2)
void gemm_all(const float* __restrict__ topic, const float* __restrict__ image,
              const float* __restrict__ text,  const float* __restrict__ Wq,
              const float* __restrict__ Wv,
              const float* __restrict__ bq, const float* __restrict__ bv,
              bf16_t* __restrict__ Vws, float* __restrict__ Qws)
{
    __shared__ bf16_t Al[2][128 * 64];   // 16 KB each
    __shared__ bf16_t Bl[2][192 * 64];   // 24 KB each

    // XCD-chunked bijective remap, nwg = 772 (q=96, r=4) [T1/m204]
    const int b0 = blockIdx.x;
    const int xcd = b0 & 7, ii = b0 >> 3;
    const int bid = (xcd < 4) ? (xcd * 97 + ii) : (388 + (xcd - 4) * 96 + ii);

    const int tid = threadIdx.x;
    const bool isQ = (bid >= 768);
    int s, tm, tn;
    if (isQ) { s = S_; tm = 0; tn = bid - 768; }
    else     { s = bid / 12; const int t = bid % 12; tn = t / 3; tm = t % 3; }

    const float* Apanel;
    if (isQ || tm == 0) Apanel = topic;
    else if (tm == 1)   Apanel = image + (size_t)s * B_ * H_;
    else                Apanel = text  + (size_t)s * B_ * H_;
    const float* Wbase = (isQ ? Wq : (Wv + (size_t)s * H_ * A_)) + tn * 192;

    const int wv = tid >> 6, lane = tid & 63;
    const int wr = wv >> 2, wc = wv & 3;          // wave tile: 64 rows x 48 cols
    const int fr = lane & 15, fg = lane >> 4;

    // A staging map: row ar = tid>>2 (0..127), 16 k's at akq = (tid&3)*16
    const int ar  = tid >> 2;
    const int akq = (tid & 3) * 16;
    const float* Ap = Apanel + (size_t)ar * H_ + akq;
    // W staging map: k-pair wk0 = 2*(tid>>4), 12 n's at wg*4 + 64j
    const int wg  = tid & 15;
    const int wk0 = 2 * (tid >> 4);
    const float* Wp = Wbase + (size_t)wk0 * A_ + wg * 4;

    f32x4 acc[4][3];
    #pragma unroll
    for (int i = 0; i < 4; ++i)
        #pragma unroll
        for (int j = 0; j < 3; ++j)
            acc[i][j] = (f32x4){0.f, 0.f, 0.f, 0.f};

    f32x4 areg[4];               // 16 f32: A[ar][akq..akq+15], 1-iter window
    f32x4 wreg0[6], wreg1[6];    // W double set: 2-iter window

    auto loadA = [&](int t1) {
        const float* p = Ap + t1 * 64;
        #pragma unroll
        for (int i = 0; i < 4; ++i)
            areg[i] = *reinterpret_cast<const f32x4*>(p + 4 * i);
    };
    auto loadW0 = [&](int t1) {
        const float* p = Wp + (size_t)(t1 * 64) * A_;
        #pragma unroll
        for (int j = 0; j < 3; ++j) {
            wreg0[2*j]   = *reinterpret_cast<const f32x4*>(p +      64 * j);
            wreg0[2*j+1] = *reinterpret_cast<const f32x4*>(p + A_ + 64 * j);
        }
    };
    auto loadW1 = [&](int t1) {
        const float* p = Wp + (size_t)(t1 * 64) * A_;
        #pragma unroll
        for (int j = 0; j < 3; ++j) {
            wreg1[2*j]   = *reinterpret_cast<const f32x4*>(p +      64 * j);
            wreg1[2*j+1] = *reinterpret_cast<const f32x4*>(p + A_ + 64 * j);
        }
    };
    auto writeA = [&](int buf) {       // 2 x ds_write_b128, swizzle c^(ar&7)
        const int c0 = (tid & 3) * 2;
        #pragma unroll
        for (int q = 0; q < 2; ++q) {
            const int cs = (c0 + q) ^ (ar & 7);
            *reinterpret_cast<bf16x8*>(&Al[buf][ar * 64 + cs * 8]) =
                pack8(areg[2*q], areg[2*q+1]);
        }
    };
    auto writeB0 = [&](int buf) {      // 12 x ds_write_b32, key (n^(n>>3))&7
        #pragma unroll
        for (int j = 0; j < 3; ++j)
            #pragma unroll
            for (int i = 0; i < 4; ++i) {
                const int n   = wg * 4 + 64 * j + i;
                const int key = (n ^ (n >> 3)) & 7;
                const int kx  = (((wk0 >> 3) ^ key) << 3) + (wk0 & 7);
                bf16x2 pr;
                pr[0] = (bf16_t)wreg0[2*j][i];
                pr[1] = (bf16_t)wreg0[2*j+1][i];
                *reinterpret_cast<bf16x2*>(&Bl[buf][n * 64 + kx]) = pr;
            }
    };
    auto writeB1 = [&](int buf) {
        #pragma unroll
        for (int j = 0; j < 3; ++j)
            #pragma unroll
            for (int i = 0; i < 4; ++i) {
                const int n   = wg * 4 + 64 * j + i;
                const int key = (n ^ (n >> 3)) & 7;
                const int kx  = (((wk0 >> 3) ^ key) << 3) + (wk0 & 7);
                bf16x2 pr;
                pr[0] = (bf16_t)wreg1[2*j][i];
                pr[1] = (bf16_t)wreg1[2*j+1][i];
                *reinterpret_cast<bf16x2*>(&Bl[buf][n * 64 + kx]) = pr;
            }
    };

    // ---- prologue: tile 0 staged; tiles 1 (A,W1) and 2 (W0) in flight ----
    loadW0(0); loadA(0);
    writeB0(0); writeA(0);            // reg-dep waits tile 0 only
    loadW1(1); loadA(1);
    loadW0(2);
    asm volatile("s_waitcnt lgkmcnt(0)" ::: "memory");
    __builtin_amdgcn_sched_barrier(0);
    __builtin_amdgcn_s_barrier();
    __builtin_amdgcn_sched_barrier(0);

    #pragma unroll
    for (int t = 0; t < 12; ++t) {
        const int cur = t & 1, nxt = cur ^ 1;
        // write tile t+1: W from set[(t+1)&1] (loaded 2 iters ago), A 1 iter ago
        if (t < 11) {
            if (((t + 1) & 1) == 0) writeB0(nxt); else writeB1(nxt);
            writeA(nxt);
        }
        // refill: W tile t+3 into the just-freed set; A tile t+2
        if (t <= 8) {
            if (((t + 1) & 1) == 0) loadW0(t + 3); else loadW1(t + 3);
        }
        if (t < 10) loadA(t + 2);
        __builtin_amdgcn_sched_barrier(0);          // pin loads above compute

        #pragma unroll
        for (int kk = 0; kk < 2; ++kk) {
            bf16x8 af[4], bf_[3];
            const int kb = kk * 4 + fg;
            #pragma unroll
            for (int mi = 0; mi < 4; ++mi) {
                const int m = wr * 64 + mi * 16 + fr;
                af[mi] = *reinterpret_cast<const bf16x8*>(
                    &Al[cur][m * 64 + ((kb ^ (m & 7)) << 3)]);
            }
            #pragma unroll
            for (int ni = 0; ni < 3; ++ni) {
                const int n   = wc * 48 + ni * 16 + fr;
                const int key = (n ^ (n >> 3)) & 7;
                bf_[ni] = *reinterpret_cast<const bf16x8*>(
                    &Bl[cur][n * 64 + ((kb ^ key) << 3)]);
            }
            #pragma unroll
            for (int mi = 0; mi < 4; ++mi)
                #pragma unroll
                for (int ni = 0; ni < 3; ++ni)
                    acc[mi][ni] = __builtin_amdgcn_mfma_f32_16x16x32_bf16(
                        af[mi], bf_[ni], acc[mi][ni], 0, 0, 0);
        }

        if (t < 11) {                  // lgkm-only barrier: loads stay in flight
            asm volatile("s_waitcnt lgkmcnt(0)" ::: "memory");
            __builtin_amdgcn_sched_barrier(0);
            __builtin_amdgcn_s_barrier();
            __builtin_amdgcn_sched_barrier(0);
        }
    }

    // ---- epilogue: C/D map col = lane&15, row = (lane>>4)*4 + j ----
    if (isQ) {
        #pragma unroll
        for (int ni = 0; ni < 3; ++ni) {
            const int n = tn * 192 + wc * 48 + ni * 16 + fr;
            const float bias = bq[n];
            #pragma unroll
            for (int mi = 0; mi < 4; ++mi)
                #pragma unroll
                for (int j = 0; j < 4; ++j) {
                    const int m = wr * 64 + mi * 16 + fg * 4 + j;
                    Qws[(size_t)m * A_ + n] = acc[mi][ni][j] + bias;
                }
        }
    } else {
        const float* bvrow = bv + (size_t)s * A_;
        #pragma unroll
        for (int ni = 0; ni < 3; ++ni) {
            const int n = tn * 192 + wc * 48 + ni * 16 + fr;
            const float bias = bvrow[n];
            #pragma unroll
            for (int mi = 0; mi < 4; ++mi)
                #pragma unroll
                for (int j = 0; j < 4; ++j) {
                    const int b = wr * 64 + mi * 16 + fg * 4 + j;
                    Vws[(((size_t)s * B_ + b) * 3 + tm) * A_ + n] = (bf16_t)(acc[mi][ni][j] + bias);
                }
        }
    }
}

// ---- attention combine: one wave per (s,b) ----
__global__ __launch_bounds__(256)
void mm_attn_kernel(const bf16_t* __restrict__ Vws,
                    const float* __restrict__ Qws,
                    float* __restrict__ out)
{
    const int wave = threadIdx.x >> 6;
    const int lane = threadIdx.x & 63;
    const int p = blockIdx.x * 4 + wave;
    const int s = p >> 7;
    const int b = p & 127;
    const float*  qrow  = Qws + (size_t)b * A_;
    const bf16_t* vbase = Vws + ((size_t)s * B_ + b) * 3 * A_;

    float4 qv[3];
    bf16x4 vv[3][3];
    float p0 = 0.f, p1 = 0.f, p2 = 0.f;
    #pragma unroll
    for (int j = 0; j < 3; ++j) {
        const int a = lane * 4 + j * 256;
        qv[j]    = *reinterpret_cast<const float4*>(qrow + a);
        vv[0][j] = *reinterpret_cast<const bf16x4*>(vbase + 0*A_ + a);
        vv[1][j] = *reinterpret_cast<const bf16x4*>(vbase + 1*A_ + a);
        vv[2][j] = *reinterpret_cast<const bf16x4*>(vbase + 2*A_ + a);
        p0 += qv[j].x*(float)vv[0][j][0] + qv[j].y*(float)vv[0][j][1]
            + qv[j].z*(float)vv[0][j][2] + qv[j].w*(float)vv[0][j][3];
        p1 += qv[j].x*(float)vv[1][j][0] + qv[j].y*(float)vv[1][j][1]
            + qv[j].z*(float)vv[1][j][2] + qv[j].w*(float)vv[1][j][3];
        p2 += qv[j].x*(float)vv[2][j][0] + qv[j].y*(float)vv[2][j][1]
            + qv[j].z*(float)vv[2][j][2] + qv[j].w*(float)vv[2][j][3];
    }
    #pragma unroll
    for (int d = 1; d < 64; d <<= 1) {
        p0 += __shfl_xor(p0, d);
        p1 += __shfl_xor(p1, d);
        p2 += __shfl_xor(p2, d);
    }
    const float norm = 0.03608439182435161f;   // 1/sqrt(768)
    const float s0 = p0 * norm, s1 = p1 * norm, s2 = p2 * norm;
    const float mx = fmaxf(s0, fmaxf(s1, s2));
    const float e0 = expf(s0 - mx), e1 = expf(s1 - mx), e2 = expf(s2 - mx);
    const float inv = 1.f / (e0 + e1 + e2);
    const float a0 = e0 * inv, a1 = e1 * inv, a2 = e2 * inv;

    float* orow = out + ((size_t)s * B_ + b) * A_;
    #pragma unroll
    for (int j = 0; j < 3; ++j) {
        const int a = lane * 4 + j * 256;
        float4 o;
        o.x = a0*(float)vv[0][j][0] + a1*(float)vv[1][j][0] + a2*(float)vv[2][j][0];
        o.y = a0*(float)vv[0][j][1] + a1*(float)vv[1][j][1] + a2*(float)vv[2][j][1];
        o.z = a0*(float)vv[0][j][2] + a1*(float)vv[1][j][2] + a2*(float)vv[2][j][2];
        o.w = a0*(float)vv[0][j][3] + a1*(float)vv[1][j][3] + a2*(float)vv[2][j][3];
        *reinterpret_cast<float4*>(orow + a) = o;
    }
}

// ============================================================================
// FALLBACK PATH (round-1 GEMM, used only if ws_size is too small)
// ============================================================================
#define LDSPAD 40
__global__ __launch_bounds__(256, 2)
void mm_gemm_kernel(const float* __restrict__ topic,
                    const float* __restrict__ image,
                    const float* __restrict__ text,
                    const float* __restrict__ Wq,
                    const float* __restrict__ bq,
                    const float* __restrict__ Wv,
                    const float* __restrict__ bv,
                    bf16_t* __restrict__ Vws,
                    float*  __restrict__ Qws)
{
    __shared__ bf16_t Alds[128][LDSPAD];
    __shared__ bf16_t Blds[128][LDSPAD];

    const int bid = blockIdx.x;
    const int tid = threadIdx.x;
    const bool isQ = (bid >= S_ * 18);
    int s, tm, tn;
    if (isQ) { s = 0; tm = 0; tn = bid - S_ * 18; }
    else     { s = bid / 18; const int t = bid % 18; tm = t / 6; tn = t % 6; }

    const int ar  = tid >> 1;
    const int aks = (tid & 1) * 16;
    const float* arow;
    if (isQ) {
        arow = topic + (size_t)ar * H_;
    } else {
        const int am  = tm * 128 + ar;
        const int sel = am >> 7;
        const int b   = am & 127;
        if (sel == 0)      arow = topic + (size_t)b * H_;
        else if (sel == 1) arow = image + ((size_t)s * B_ + b) * H_;
        else               arow = text  + ((size_t)s * B_ + b) * H_;
    }
    const int arot = (ar >> 3) & 3;

    const int bn  = tid & 127;
    const int bks = (tid >> 7) * 16;
    const float* wbase = isQ ? Wq : (Wv + (size_t)s * H_ * A_);
    const float* bcolp = wbase + (size_t)(tn * 128 + bn);
    const int brot = (bn >> 3) & 3;

    const int wave = tid >> 6;
    const int lane = tid & 63;
    const int wr = wave >> 1;
    const int wc = wave & 1;
    const int fr = lane & 15;
    const int fg = lane >> 4;

    f32x4 acc[4][4];
    #pragma unroll
    for (int i = 0; i < 4; ++i)
        #pragma unroll
        for (int j = 0; j < 4; ++j)
            acc[i][j] = (f32x4){0.f, 0.f, 0.f, 0.f};

    for (int k0 = 0; k0 < H_; k0 += 32) {
        float4 av[4];
        const float4* ap = reinterpret_cast<const float4*>(arow + k0 + aks);
        #pragma unroll
        for (int i = 0; i < 4; ++i) av[i] = ap[i];
        float bvr[16];
        #pragma unroll
        for (int j = 0; j < 16; ++j) bvr[j] = bcolp[(size_t)(k0 + bks + j) * A_];

        __syncthreads();

        #pragma unroll
        for (int i = 0; i < 4; ++i) {
            const int j = (i + arot) & 3;
            bf16x4 c;
            c[0] = (bf16_t)av[j].x; c[1] = (bf16_t)av[j].y;
            c[2] = (bf16_t)av[j].z; c[3] = (bf16_t)av[j].w;
            *reinterpret_cast<bf16x4*>(&Alds[ar][aks + 4*j]) = c;
        }
        #pragma unroll
        for (int i = 0; i < 4; ++i) {
            const int j = (i + brot) & 3;
            bf16x4 c;
            c[0] = (bf16_t)bvr[4*j+0]; c[1] = (bf16_t)bvr[4*j+1];
            c[2] = (bf16_t)bvr[4*j+2]; c[3] = (bf16_t)bvr[4*j+3];
            *reinterpret_cast<bf16x4*>(&Blds[bn][bks + 4*j]) = c;
        }
        __syncthreads();

        bf16x8 afrag[4], bfrag[4];
        #pragma unroll
        for (int mi = 0; mi < 4; ++mi)
            afrag[mi] = *reinterpret_cast<const bf16x8*>(&Alds[wr*64 + mi*16 + fr][fg*8]);
        #pragma unroll
        for (int ni = 0; ni < 4; ++ni)
            bfrag[ni] = *reinterpret_cast<const bf16x8*>(&Blds[wc*64 + ni*16 + fr][fg*8]);
        #pragma unroll
        for (int mi = 0; mi < 4; ++mi)
            #pragma unroll
            for (int ni = 0; ni < 4; ++ni)
                acc[mi][ni] = __builtin_amdgcn_mfma_f32_16x16x32_bf16(
                    afrag[mi], bfrag[ni], acc[mi][ni], 0, 0, 0);
    }

    if (isQ) {
        #pragma unroll
        for (int ni = 0; ni < 4; ++ni) {
            const int n = tn*128 + wc*64 + ni*16 + fr;
            const float bias = bq[n];
            #pragma unroll
            for (int mi = 0; mi < 4; ++mi)
                #pragma unroll
                for (int j = 0; j < 4; ++j) {
                    const int m = wr*64 + mi*16 + fg*4 + j;
                    Qws[(size_t)m * A_ + n] = acc[mi][ni][j] + bias;
                }
        }
    } else {
        const float* bvrow = bv + (size_t)s * A_;
        #pragma unroll
        for (int ni = 0; ni < 4; ++ni) {
            const int n = tn*128 + wc*64 + ni*16 + fr;
            const float bias = bvrow[n];
            #pragma unroll
            for (int mi = 0; mi < 4; ++mi)
                #pragma unroll
                for (int j = 0; j < 4; ++j) {
                    const int b = wr*64 + mi*16 + fg*4 + j;
                    Vws[(((size_t)s * B_ + b) * 3 + tm) * A_ + n] = (bf16_t)(acc[mi][ni][j] + bias);
                }
        }
    }
}

// ============================================================================
extern "C" void kernel_launch(void* const* d_in, const int* in_sizes, int n_in,
                              void* d_out, int out_size, void* d_ws, size_t ws_size,
                              hipStream_t stream)
{
    const float* topic = (const float*)d_in[0];
    const float* image = (const float*)d_in[1];
    const float* text  = (const float*)d_in[2];
    const float* Wq    = (const float*)d_in[3];
    const float* bq    = (const float*)d_in[4];
    const float* Wv    = (const float*)d_in[5];
    const float* bv    = (const float*)d_in[6];
    float* out = (float*)d_out;

    const size_t szV = (size_t)S_ * B_ * 3 * A_ * sizeof(bf16_t);   // 37,748,736
    const size_t szQ = (size_t)B_ * A_ * sizeof(float);             //    393,216
    const size_t need = szV + szQ;                                  // ~38.1 MB

    if (ws_size >= need) {
        bf16_t* Vws = (bf16_t*)d_ws;
        float*  Qws = (float*)((char*)d_ws + szV);
        gemm_all<<<772, 512, 0, stream>>>(topic, image, text, Wq, Wv, bq, bv, Vws, Qws);
        mm_attn_kernel<<<S_ * B_ / 4, 256, 0, stream>>>(Vws, Qws, out);
    } else {
        bf16_t* Vws = (bf16_t*)d_ws;
        float*  Qws = (float*)((char*)d_ws + szV);
        mm_gemm_kernel<<<S_ * 18 + 6, 256, 0, stream>>>(topic, image, text, Wq, bq, Wv, bv, Vws, Qws);
        mm_attn_kernel<<<S_ * B_ / 4, 256, 0, stream>>>(Vws, Qws, out);
    }
}

// Round 18
// 82.274 us; speedup vs baseline: 1.0308x; 1.0308x over previous
//
#include <hip/hip_runtime.h>
#include <hip/hip_bf16.h>
#include <math.h>

#define S_ 64
#define B_ 128
#define H_ 768
#define A_ 768

typedef __bf16 bf16_t;
typedef __attribute__((ext_vector_type(8))) __bf16 bf16x8;
typedef __attribute__((ext_vector_type(4))) __bf16 bf16x4;
typedef __attribute__((ext_vector_type(2))) __bf16 bf16x2;
typedef __attribute__((ext_vector_type(4))) float f32x4;

__device__ __forceinline__ bf16x8 pack8(f32x4 a, f32x4 b) {
    bf16x8 o;
    o[0]=(bf16_t)a[0]; o[1]=(bf16_t)a[1]; o[2]=(bf16_t)a[2]; o[3]=(bf16_t)a[3];
    o[4]=(bf16_t)b[0]; o[5]=(bf16_t)b[1]; o[6]=(bf16_t)b[2]; o[7]=(bf16_t)b[3];
    return o;
}

// ============================================================================
// FAST PATH: single fused GEMM (reads raw f32 inputs; no prep passes) + attn
// FINAL = r15 (82.3 us best). Ledger: T1 xcd-chunk(+), both-side swizzle(+),
// 2-phase write-early/load-late(+), (512,2) spill fix(+), tn-major(+);
// T4 counted-vmcnt / T5 setprio / 2-deep staging: null; persistence /
// BM384 / 1-block-CU: negative. attn kernel is at HBM BW roofline.
// ============================================================================

// BM=128 x BN=192, BK=64, 512 thr (8 waves, 2M x 4N), 24 MFMA/wave/K-step.
// Write-early/load-late: iter t = { ds_write LDS[nxt] from regs (tile t+1,
// loaded at t-1, full-iteration latency window); issue tile t+2 loads;
// MFMA on LDS[cur]; lgkm-only barrier (loads stay in flight) }.
// __launch_bounds__(512, 2): 2nd arg = min BLOCKS/CU on this toolchain;
// 2 -> 128-VGPR cap (VGPR=84, no spill), matches 80KB-LDS occupancy.
__global__ __launch_bounds__(512, 2)
void gemm_all(const float* __restrict__ topic, const float* __restrict__ image,
              const float* __restrict__ text,  const float* __restrict__ Wq,
              const float* __restrict__ Wv,
              const float* __restrict__ bq, const float* __restrict__ bv,
              bf16_t* __restrict__ Vws, float* __restrict__ Qws)
{
    __shared__ bf16_t Al[2][128 * 64];   // 16 KB each
    __shared__ bf16_t Bl[2][192 * 64];   // 24 KB each

    // XCD-chunked bijective remap, nwg = 772 (q=96, r=4) [T1/m204]
    const int b0 = blockIdx.x;
    const int xcd = b0 & 7, ii = b0 >> 3;
    const int bid = (xcd < 4) ? (xcd * 97 + ii) : (388 + (xcd - 4) * 96 + ii);

    const int tid = threadIdx.x;
    const bool isQ = (bid >= 768);
    int s, tm, tn;
    if (isQ) { s = S_; tm = 0; tn = bid - 768; }
    else     { s = bid / 12; const int t = bid % 12; tn = t / 3; tm = t % 3; }

    const float* Apanel;
    if (isQ || tm == 0) Apanel = topic;
    else if (tm == 1)   Apanel = image + (size_t)s * B_ * H_;
    else                Apanel = text  + (size_t)s * B_ * H_;
    const float* Wbase = (isQ ? Wq : (Wv + (size_t)s * H_ * A_)) + tn * 192;

    const int wv = tid >> 6, lane = tid & 63;
    const int wr = wv >> 2, wc = wv & 3;          // wave tile: 64 rows x 48 cols
    const int fr = lane & 15, fg = lane >> 4;

    // A staging map: row ar = tid>>2 (0..127), 16 k's at akq = (tid&3)*16
    const int ar  = tid >> 2;
    const int akq = (tid & 3) * 16;
    const float* Ap = Apanel + (size_t)ar * H_ + akq;
    // W staging map: k-pair wk0 = 2*(tid>>4), 12 n's at wg*4 + 64j
    const int wg  = tid & 15;
    const int wk0 = 2 * (tid >> 4);
    const float* Wp = Wbase + (size_t)wk0 * A_ + wg * 4;

    f32x4 acc[4][3];
    #pragma unroll
    for (int i = 0; i < 4; ++i)
        #pragma unroll
        for (int j = 0; j < 3; ++j)
            acc[i][j] = (f32x4){0.f, 0.f, 0.f, 0.f};

    f32x4 areg[4];     // 16 f32: A[ar][akq..akq+15]
    f32x4 wreg[6];     // 2 k-rows x 12 n's

    auto loadA = [&](int t1) {
        const float* p = Ap + t1 * 64;
        #pragma unroll
        for (int i = 0; i < 4; ++i)
            areg[i] = *reinterpret_cast<const f32x4*>(p + 4 * i);
    };
    auto loadW = [&](int t1) {
        const float* p = Wp + (size_t)(t1 * 64) * A_;
        #pragma unroll
        for (int j = 0; j < 3; ++j) {
            wreg[2*j]   = *reinterpret_cast<const f32x4*>(p +      64 * j);
            wreg[2*j+1] = *reinterpret_cast<const f32x4*>(p + A_ + 64 * j);
        }
    };
    auto writeA = [&](int buf) {       // 2 x ds_write_b128, swizzle c^(ar&7)
        const int c0 = (tid & 3) * 2;
        #pragma unroll
        for (int q = 0; q < 2; ++q) {
            const int cs = (c0 + q) ^ (ar & 7);
            *reinterpret_cast<bf16x8*>(&Al[buf][ar * 64 + cs * 8]) =
                pack8(areg[2*q], areg[2*q+1]);
        }
    };
    auto writeB = [&](int buf) {       // 12 x ds_write_b32, key (n^(n>>3))&7
        #pragma unroll
        for (int j = 0; j < 3; ++j)
            #pragma unroll
            for (int i = 0; i < 4; ++i) {
                const int n   = wg * 4 + 64 * j + i;
                const int key = (n ^ (n >> 3)) & 7;
                const int kx  = (((wk0 >> 3) ^ key) << 3) + (wk0 & 7);
                bf16x2 pr;
                pr[0] = (bf16_t)wreg[2*j][i];
                pr[1] = (bf16_t)wreg[2*j+1][i];
                *reinterpret_cast<bf16x2*>(&Bl[buf][n * 64 + kx]) = pr;
            }
    };

    // ---- prologue: tile 0 staged, tile 1 loads in flight ----
    loadA(0); loadW(0);
    writeA(0); writeB(0);
    loadA(1); loadW(1);
    asm volatile("s_waitcnt lgkmcnt(0)" ::: "memory");
    __builtin_amdgcn_sched_barrier(0);
    __builtin_amdgcn_s_barrier();
    __builtin_amdgcn_sched_barrier(0);

    #pragma unroll
    for (int t = 0; t < 12; ++t) {
        const int cur = t & 1, nxt = cur ^ 1;
        if (t < 11) { writeA(nxt); writeB(nxt); }   // tile t+1 (regs a full iter old)
        if (t < 10) { loadA(t + 2); loadW(t + 2); } // refill regs
        __builtin_amdgcn_sched_barrier(0);          // pin loads above compute

        #pragma unroll
        for (int kk = 0; kk < 2; ++kk) {
            bf16x8 af[4], bf_[3];
            const int kb = kk * 4 + fg;
            #pragma unroll
            for (int mi = 0; mi < 4; ++mi) {
                const int m = wr * 64 + mi * 16 + fr;
                af[mi] = *reinterpret_cast<const bf16x8*>(
                    &Al[cur][m * 64 + ((kb ^ (m & 7)) << 3)]);
            }
            #pragma unroll
            for (int ni = 0; ni < 3; ++ni) {
                const int n   = wc * 48 + ni * 16 + fr;
                const int key = (n ^ (n >> 3)) & 7;
                bf_[ni] = *reinterpret_cast<const bf16x8*>(
                    &Bl[cur][n * 64 + ((kb ^ key) << 3)]);
            }
            #pragma unroll
            for (int mi = 0; mi < 4; ++mi)
                #pragma unroll
                for (int ni = 0; ni < 3; ++ni)
                    acc[mi][ni] = __builtin_amdgcn_mfma_f32_16x16x32_bf16(
                        af[mi], bf_[ni], acc[mi][ni], 0, 0, 0);
        }

        if (t < 11) {                  // lgkm-only barrier: loads stay in flight
            asm volatile("s_waitcnt lgkmcnt(0)" ::: "memory");
            __builtin_amdgcn_sched_barrier(0);
            __builtin_amdgcn_s_barrier();
            __builtin_amdgcn_sched_barrier(0);
        }
    }

    // ---- epilogue: C/D map col = lane&15, row = (lane>>4)*4 + j ----
    if (isQ) {
        #pragma unroll
        for (int ni = 0; ni < 3; ++ni) {
            const int n = tn * 192 + wc * 48 + ni * 16 + fr;
            const float bias = bq[n];
            #pragma unroll
            for (int mi = 0; mi < 4; ++mi)
                #pragma unroll
                for (int j = 0; j < 4; ++j) {
                    const int m = wr * 64 + mi * 16 + fg * 4 + j;
                    Qws[(size_t)m * A_ + n] = acc[mi][ni][j] + bias;
                }
        }
    } else {
        const float* bvrow = bv + (size_t)s * A_;
        #pragma unroll
        for (int ni = 0; ni < 3; ++ni) {
            const int n = tn * 192 + wc * 48 + ni * 16 + fr;
            const float bias = bvrow[n];
            #pragma unroll
            for (int mi = 0; mi < 4; ++mi)
                #pragma unroll
                for (int j = 0; j < 4; ++j) {
                    const int b = wr * 64 + mi * 16 + fg * 4 + j;
                    Vws[(((size_t)s * B_ + b) * 3 + tm) * A_ + n] = (bf16_t)(acc[mi][ni][j] + bias);
                }
        }
    }
}

// ---- attention combine: one wave per (s,b); at HBM BW roofline ----
__global__ __launch_bounds__(256)
void mm_attn_kernel(const bf16_t* __restrict__ Vws,
                    const float* __restrict__ Qws,
                    float* __restrict__ out)
{
    const int wave = threadIdx.x >> 6;
    const int lane = threadIdx.x & 63;
    const int p = blockIdx.x * 4 + wave;
    const int s = p >> 7;
    const int b = p & 127;
    const float*  qrow  = Qws + (size_t)b * A_;
    const bf16_t* vbase = Vws + ((size_t)s * B_ + b) * 3 * A_;

    float4 qv[3];
    bf16x4 vv[3][3];
    float p0 = 0.f, p1 = 0.f, p2 = 0.f;
    #pragma unroll
    for (int j = 0; j < 3; ++j) {
        const int a = lane * 4 + j * 256;
        qv[j]    = *reinterpret_cast<const float4*>(qrow + a);
        vv[0][j] = *reinterpret_cast<const bf16x4*>(vbase + 0*A_ + a);
        vv[1][j] = *reinterpret_cast<const bf16x4*>(vbase + 1*A_ + a);
        vv[2][j] = *reinterpret_cast<const bf16x4*>(vbase + 2*A_ + a);
        p0 += qv[j].x*(float)vv[0][j][0] + qv[j].y*(float)vv[0][j][1]
            + qv[j].z*(float)vv[0][j][2] + qv[j].w*(float)vv[0][j][3];
        p1 += qv[j].x*(float)vv[1][j][0] + qv[j].y*(float)vv[1][j][1]
            + qv[j].z*(float)vv[1][j][2] + qv[j].w*(float)vv[1][j][3];
        p2 += qv[j].x*(float)vv[2][j][0] + qv[j].y*(float)vv[2][j][1]
            + qv[j].z*(float)vv[2][j][2] + qv[j].w*(float)vv[2][j][3];
    }
    #pragma unroll
    for (int d = 1; d < 64; d <<= 1) {
        p0 += __shfl_xor(p0, d);
        p1 += __shfl_xor(p1, d);
        p2 += __shfl_xor(p2, d);
    }
    const float norm = 0.03608439182435161f;   // 1/sqrt(768)
    const float s0 = p0 * norm, s1 = p1 * norm, s2 = p2 * norm;
    const float mx = fmaxf(s0, fmaxf(s1, s2));
    const float e0 = expf(s0 - mx), e1 = expf(s1 - mx), e2 = expf(s2 - mx);
    const float inv = 1.f / (e0 + e1 + e2);
    const float a0 = e0 * inv, a1 = e1 * inv, a2 = e2 * inv;

    float* orow = out + ((size_t)s * B_ + b) * A_;
    #pragma unroll
    for (int j = 0; j < 3; ++j) {
        const int a = lane * 4 + j * 256;
        float4 o;
        o.x = a0*(float)vv[0][j][0] + a1*(float)vv[1][j][0] + a2*(float)vv[2][j][0];
        o.y = a0*(float)vv[0][j][1] + a1*(float)vv[1][j][1] + a2*(float)vv[2][j][1];
        o.z = a0*(float)vv[0][j][2] + a1*(float)vv[1][j][2] + a2*(float)vv[2][j][2];
        o.w = a0*(float)vv[0][j][3] + a1*(float)vv[1][j][3] + a2*(float)vv[2][j][3];
        *reinterpret_cast<float4*>(orow + a) = o;
    }
}

// ============================================================================
// FALLBACK PATH (round-1 GEMM, used only if ws_size is too small)
// ============================================================================
#define LDSPAD 40
__global__ __launch_bounds__(256, 2)
void mm_gemm_kernel(const float* __restrict__ topic,
                    const float* __restrict__ image,
                    const float* __restrict__ text,
                    const float* __restrict__ Wq,
                    const float* __restrict__ bq,
                    const float* __restrict__ Wv,
                    const float* __restrict__ bv,
                    bf16_t* __restrict__ Vws,
                    float*  __restrict__ Qws)
{
    __shared__ bf16_t Alds[128][LDSPAD];
    __shared__ bf16_t Blds[128][LDSPAD];

    const int bid = blockIdx.x;
    const int tid = threadIdx.x;
    const bool isQ = (bid >= S_ * 18);
    int s, tm, tn;
    if (isQ) { s = 0; tm = 0; tn = bid - S_ * 18; }
    else     { s = bid / 18; const int t = bid % 18; tm = t / 6; tn = t % 6; }

    const int ar  = tid >> 1;
    const int aks = (tid & 1) * 16;
    const float* arow;
    if (isQ) {
        arow = topic + (size_t)ar * H_;
    } else {
        const int am  = tm * 128 + ar;
        const int sel = am >> 7;
        const int b   = am & 127;
        if (sel == 0)      arow = topic + (size_t)b * H_;
        else if (sel == 1) arow = image + ((size_t)s * B_ + b) * H_;
        else               arow = text  + ((size_t)s * B_ + b) * H_;
    }
    const int arot = (ar >> 3) & 3;

    const int bn  = tid & 127;
    const int bks = (tid >> 7) * 16;
    const float* wbase = isQ ? Wq : (Wv + (size_t)s * H_ * A_);
    const float* bcolp = wbase + (size_t)(tn * 128 + bn);
    const int brot = (bn >> 3) & 3;

    const int wave = tid >> 6;
    const int lane = tid & 63;
    const int wr = wave >> 1;
    const int wc = wave & 1;
    const int fr = lane & 15;
    const int fg = lane >> 4;

    f32x4 acc[4][4];
    #pragma unroll
    for (int i = 0; i < 4; ++i)
        #pragma unroll
        for (int j = 0; j < 4; ++j)
            acc[i][j] = (f32x4){0.f, 0.f, 0.f, 0.f};

    for (int k0 = 0; k0 < H_; k0 += 32) {
        float4 av[4];
        const float4* ap = reinterpret_cast<const float4*>(arow + k0 + aks);
        #pragma unroll
        for (int i = 0; i < 4; ++i) av[i] = ap[i];
        float bvr[16];
        #pragma unroll
        for (int j = 0; j < 16; ++j) bvr[j] = bcolp[(size_t)(k0 + bks + j) * A_];

        __syncthreads();

        #pragma unroll
        for (int i = 0; i < 4; ++i) {
            const int j = (i + arot) & 3;
            bf16x4 c;
            c[0] = (bf16_t)av[j].x; c[1] = (bf16_t)av[j].y;
            c[2] = (bf16_t)av[j].z; c[3] = (bf16_t)av[j].w;
            *reinterpret_cast<bf16x4*>(&Alds[ar][aks + 4*j]) = c;
        }
        #pragma unroll
        for (int i = 0; i < 4; ++i) {
            const int j = (i + brot) & 3;
            bf16x4 c;
            c[0] = (bf16_t)bvr[4*j+0]; c[1] = (bf16_t)bvr[4*j+1];
            c[2] = (bf16_t)bvr[4*j+2]; c[3] = (bf16_t)bvr[4*j+3];
            *reinterpret_cast<bf16x4*>(&Blds[bn][bks + 4*j]) = c;
        }
        __syncthreads();

        bf16x8 afrag[4], bfrag[4];
        #pragma unroll
        for (int mi = 0; mi < 4; ++mi)
            afrag[mi] = *reinterpret_cast<const bf16x8*>(&Alds[wr*64 + mi*16 + fr][fg*8]);
        #pragma unroll
        for (int ni = 0; ni < 4; ++ni)
            bfrag[ni] = *reinterpret_cast<const bf16x8*>(&Blds[wc*64 + ni*16 + fr][fg*8]);
        #pragma unroll
        for (int mi = 0; mi < 4; ++mi)
            #pragma unroll
            for (int ni = 0; ni < 4; ++ni)
                acc[mi][ni] = __builtin_amdgcn_mfma_f32_16x16x32_bf16(
                    afrag[mi], bfrag[ni], acc[mi][ni], 0, 0, 0);
    }

    if (isQ) {
        #pragma unroll
        for (int ni = 0; ni < 4; ++ni) {
            const int n = tn*128 + wc*64 + ni*16 + fr;
            const float bias = bq[n];
            #pragma unroll
            for (int mi = 0; mi < 4; ++mi)
                #pragma unroll
                for (int j = 0; j < 4; ++j) {
                    const int m = wr*64 + mi*16 + fg*4 + j;
                    Qws[(size_t)m * A_ + n] = acc[mi][ni][j] + bias;
                }
        }
    } else {
        const float* bvrow = bv + (size_t)s * A_;
        #pragma unroll
        for (int ni = 0; ni < 4; ++ni) {
            const int n = tn*128 + wc*64 + ni*16 + fr;
            const float bias = bvrow[n];
            #pragma unroll
            for (int mi = 0; mi < 4; ++mi)
                #pragma unroll
                for (int j = 0; j < 4; ++j) {
                    const int b = wr*64 + mi*16 + fg*4 + j;
                    Vws[(((size_t)s * B_ + b) * 3 + tm) * A_ + n] = (bf16_t)(acc[mi][ni][j] + bias);
                }
        }
    }
}

// ============================================================================
extern "C" void kernel_launch(void* const* d_in, const int* in_sizes, int n_in,
                              void* d_out, int out_size, void* d_ws, size_t ws_size,
                              hipStream_t stream)
{
    const float* topic = (const float*)d_in[0];
    const float* image = (const float*)d_in[1];
    const float* text  = (const float*)d_in[2];
    const float* Wq    = (const float*)d_in[3];
    const float* bq    = (const float*)d_in[4];
    const float* Wv    = (const float*)d_in[5];
    const float* bv    = (const float*)d_in[6];
    float* out = (float*)d_out;

    const size_t szV = (size_t)S_ * B_ * 3 * A_ * sizeof(bf16_t);   // 37,748,736
    const size_t szQ = (size_t)B_ * A_ * sizeof(float);             //    393,216
    const size_t need = szV + szQ;                                  // ~38.1 MB

    if (ws_size >= need) {
        bf16_t* Vws = (bf16_t*)d_ws;
        float*  Qws = (float*)((char*)d_ws + szV);
        gemm_all<<<772, 512, 0, stream>>>(topic, image, text, Wq, Wv, bq, bv, Vws, Qws);
        mm_attn_kernel<<<S_ * B_ / 4, 256, 0, stream>>>(Vws, Qws, out);
    } else {
        bf16_t* Vws = (bf16_t*)d_ws;
        float*  Qws = (float*)((char*)d_ws + szV);
        mm_gemm_kernel<<<S_ * 18 + 6, 256, 0, stream>>>(topic, image, text, Wq, bq, Wv, bv, Vws, Qws);
        mm_attn_kernel<<<S_ * B_ / 4, 256, 0, stream>>>(Vws, Qws, out);
    }
}